// Round 1
// baseline (359.165 us; speedup 1.0000x reference)
//
#include <hip/hip_runtime.h>
#include <hip/hip_bf16.h>

#define NN 50000
#define EE 800000
#define FD 128
#define NG 128
#define NC 10
#define GBK 782   // (NN+63)/64
#define EBK 3125  // (EE+255)/256
#define NBK 196   // (NN+255)/256

typedef __attribute__((ext_vector_type(8))) short bf16x8;
typedef __attribute__((ext_vector_type(4))) float f32x4;

__device__ __forceinline__ float bf2f(unsigned short u) {
    return __uint_as_float(((unsigned int)u) << 16);
}
__device__ __forceinline__ unsigned short f2bf(float f) {
    unsigned int u = __float_as_uint(f);
    unsigned int r = (u >> 16) & 1u;
    u += 0x7fffu + r;
    return (unsigned short)(u >> 16);
}
__device__ __forceinline__ float ldf(const void* p, long i, int bf) {
    return bf ? bf2f(((const unsigned short*)p)[i]) : ((const float*)p)[i];
}

// ---------------- dtype detection ----------------
__global__ void detect_k(const unsigned short* xu, const unsigned int* eu, int* flags) {
    __shared__ int sbig, snz;
    if (threadIdx.x == 0) { sbig = 0; snz = 0; }
    __syncthreads();
    int t = threadIdx.x;
    float f = bf2f(xu[t * 2]);
    if (!(fabsf(f) < 1.0e6f)) atomicOr(&sbig, 1);
    if (eu[t * 2 + 1] != 0u) atomicOr(&snz, 1);
    __syncthreads();
    if (t == 0) {
        flags[0] = sbig ? 0 : 1;
        flags[1] = snz ? 0 : 1;
    }
}

// ---------------- params conversion + pooled zeroing ----------------
__global__ void cvt_params_k(const int* flags,
                             const void* w1, const void* b1, const void* w2, const void* b2,
                             const void* w3, const void* b3, const void* lw, const void* lb,
                             unsigned short* wt, float* bfv, float* lwf, float* lbf,
                             float* pooled) {
    int i = blockIdx.x * 256 + threadIdx.x;
    int bf = flags[0];
    if (i < 16384) pooled[i] = 0.f;   // zero the f32 pool accumulator (128 graphs x 128 feats)
    if (i < 16384) {
        int k = i >> 7, n = i & 127;
        wt[n * 128 + k] = f2bf(ldf(w1, i, bf));
    } else if (i < 32768) {
        int j = i - 16384; int k = j >> 7, n = j & 127;
        wt[16384 + n * 128 + k] = f2bf(ldf(w2, j, bf));
    } else if (i < 49152) {
        int j = i - 32768; int k = j >> 7, n = j & 127;
        wt[32768 + n * 128 + k] = f2bf(ldf(w3, j, bf));
    }
    else if (i < 49280)  bfv[i - 49152] = ldf(b1, i - 49152, bf);
    else if (i < 49408)  bfv[i - 49152] = ldf(b2, i - 49280, bf);
    else if (i < 49536)  bfv[i - 49152] = ldf(b3, i - 49408, bf);
    else if (i < 50816)  lwf[i - 49536] = ldf(lw, i - 49536, bf);
    else if (i < 50826)  lbf[i - 50816] = ldf(lb, i - 50816, bf);
}

// ---------------- scan K1: per-block sums ----------------
__global__ __launch_bounds__(256) void bsum_k(const int* deg, int* bsum) {
    __shared__ int sd[256];
    int i = blockIdx.x * 256 + threadIdx.x;
    sd[threadIdx.x] = (i < NN) ? deg[i] : 0;
    __syncthreads();
    for (int s = 128; s > 0; s >>= 1) {
        if (threadIdx.x < s) sd[threadIdx.x] += sd[threadIdx.x + s];
        __syncthreads();
    }
    if (threadIdx.x == 0) bsum[blockIdx.x] = sd[0];
}

// ---------------- scan K2: single-block exclusive scan ----------------
__global__ __launch_bounds__(256) void bscan_k(const int* bsum, int* bofs, int nblk, int* rowptr) {
    __shared__ int sb[256];
    int t = threadIdx.x;
    sb[t] = (t < nblk) ? bsum[t] : 0;
    __syncthreads();
    if (t == 0) {
        int a = 0;
        for (int b = 0; b < nblk; b++) { int v = sb[b]; sb[b] = a; a += v; }
        rowptr[NN] = a;
    }
    __syncthreads();
    if (t < nblk) bofs[t] = sb[t];
}

// ---------------- scan K3: per-block Hillis-Steele, fused dinv ----------------
__global__ __launch_bounds__(256) void scan3_k(const int* deg, const int* bofs,
                                               int* rowptr, int* pos, float* dinv) {
    __shared__ int sd[256];
    int b = blockIdx.x, t = threadIdx.x;
    int i = b * 256 + t;
    int v = (i < NN) ? deg[i] : 0;
    sd[t] = v;
    __syncthreads();
    for (int off = 1; off < 256; off <<= 1) {
        int add = (t >= off) ? sd[t - off] : 0;
        __syncthreads();
        sd[t] += add;
        __syncthreads();
    }
    int excl = bofs[b] + sd[t] - v;
    if (i < NN) {
        rowptr[i] = excl; pos[i] = excl;
        dinv[i] = rsqrtf((float)(v + 1));
    }
}

// ---------------- CSR fill ----------------
__global__ void fill_k(const int* flags, const unsigned int* eu, int* pos, unsigned short* colsrc) {
    int e = blockIdx.x * 256 + threadIdx.x;
    if (e >= EE) return;
    int s, d;
    if (flags[1]) {
        s = (int)((const uint2*)eu)[e].x;
        d = (int)((const uint2*)eu)[(long)EE + e].x;
    } else {
        s = (int)eu[e];
        d = (int)eu[EE + e];
    }
    s = ((unsigned)s < NN) ? s : 0;
    d = ((unsigned)d < NN) ? d : 0;
    int idx = atomicAdd(&pos[d], 1);
    if ((unsigned)idx < EE) colsrc[idx] = (unsigned short)s;
}

// ---------------- per-node aggregation (wave-collective; n uniform per wave) ----------------
__device__ __forceinline__ void agg_node(const unsigned short* t, int n, int lane,
                                         const float* bias, const int* rowptr,
                                         const unsigned short* colsrc, const float* dinv,
                                         float& axo, float& ayo) {
    float dn = dinv[n];
    float ax = bias[2 * lane], ay = bias[2 * lane + 1];
    unsigned int sf = ((const unsigned int*)(t + (size_t)n * 128))[lane];
    float dn2 = dn * dn;
    ax += dn2 * bf2f((unsigned short)(sf & 0xffffu));
    ay += dn2 * bf2f((unsigned short)(sf >> 16));

    int j0 = rowptr[n];
    int cnt = rowptr[n + 1] - j0;
    for (int e0 = 0; e0 < cnt; e0 += 64) {
        int m = cnt - e0; if (m > 64) m = 64;
        int idx = 0;
        if (lane < m) {
            idx = (int)colsrc[j0 + e0 + lane];
            idx = ((unsigned)idx < NN) ? idx : 0;
        }
        float dv = dinv[idx];
        int e = 0;
        for (; e + 7 < m; e += 8) {
            int s0 = __shfl(idx, e),     s1 = __shfl(idx, e + 1);
            int s2 = __shfl(idx, e + 2), s3 = __shfl(idx, e + 3);
            int s4 = __shfl(idx, e + 4), s5 = __shfl(idx, e + 5);
            int s6 = __shfl(idx, e + 6), s7 = __shfl(idx, e + 7);
            float w0 = dn * __shfl(dv, e),     w1 = dn * __shfl(dv, e + 1);
            float w2 = dn * __shfl(dv, e + 2), w3 = dn * __shfl(dv, e + 3);
            float w4 = dn * __shfl(dv, e + 4), w5 = dn * __shfl(dv, e + 5);
            float w6 = dn * __shfl(dv, e + 6), w7 = dn * __shfl(dv, e + 7);
            unsigned int v0 = ((const unsigned int*)(t + (size_t)s0 * 128))[lane];
            unsigned int v1 = ((const unsigned int*)(t + (size_t)s1 * 128))[lane];
            unsigned int v2 = ((const unsigned int*)(t + (size_t)s2 * 128))[lane];
            unsigned int v3 = ((const unsigned int*)(t + (size_t)s3 * 128))[lane];
            unsigned int v4 = ((const unsigned int*)(t + (size_t)s4 * 128))[lane];
            unsigned int v5 = ((const unsigned int*)(t + (size_t)s5 * 128))[lane];
            unsigned int v6 = ((const unsigned int*)(t + (size_t)s6 * 128))[lane];
            unsigned int v7 = ((const unsigned int*)(t + (size_t)s7 * 128))[lane];
            ax += w0 * bf2f((unsigned short)(v0 & 0xffffu)) + w1 * bf2f((unsigned short)(v1 & 0xffffu))
                + w2 * bf2f((unsigned short)(v2 & 0xffffu)) + w3 * bf2f((unsigned short)(v3 & 0xffffu))
                + w4 * bf2f((unsigned short)(v4 & 0xffffu)) + w5 * bf2f((unsigned short)(v5 & 0xffffu))
                + w6 * bf2f((unsigned short)(v6 & 0xffffu)) + w7 * bf2f((unsigned short)(v7 & 0xffffu));
            ay += w0 * bf2f((unsigned short)(v0 >> 16)) + w1 * bf2f((unsigned short)(v1 >> 16))
                + w2 * bf2f((unsigned short)(v2 >> 16)) + w3 * bf2f((unsigned short)(v3 >> 16))
                + w4 * bf2f((unsigned short)(v4 >> 16)) + w5 * bf2f((unsigned short)(v5 >> 16))
                + w6 * bf2f((unsigned short)(v6 >> 16)) + w7 * bf2f((unsigned short)(v7 >> 16));
        }
        for (; e + 3 < m; e += 4) {
            int s0 = __shfl(idx, e),     s1 = __shfl(idx, e + 1);
            int s2 = __shfl(idx, e + 2), s3 = __shfl(idx, e + 3);
            float w0 = dn * __shfl(dv, e),     w1 = dn * __shfl(dv, e + 1);
            float w2 = dn * __shfl(dv, e + 2), w3 = dn * __shfl(dv, e + 3);
            unsigned int v0 = ((const unsigned int*)(t + (size_t)s0 * 128))[lane];
            unsigned int v1 = ((const unsigned int*)(t + (size_t)s1 * 128))[lane];
            unsigned int v2 = ((const unsigned int*)(t + (size_t)s2 * 128))[lane];
            unsigned int v3 = ((const unsigned int*)(t + (size_t)s3 * 128))[lane];
            ax += w0 * bf2f((unsigned short)(v0 & 0xffffu)) + w1 * bf2f((unsigned short)(v1 & 0xffffu))
                + w2 * bf2f((unsigned short)(v2 & 0xffffu)) + w3 * bf2f((unsigned short)(v3 & 0xffffu));
            ay += w0 * bf2f((unsigned short)(v0 >> 16)) + w1 * bf2f((unsigned short)(v1 >> 16))
                + w2 * bf2f((unsigned short)(v2 >> 16)) + w3 * bf2f((unsigned short)(v3 >> 16));
        }
        for (; e < m; e++) {
            int s = __shfl(idx, e);
            float w = dn * __shfl(dv, e);
            unsigned int v = ((const unsigned int*)(t + (size_t)s * 128))[lane];
            ax += w * bf2f((unsigned short)(v & 0xffffu));
            ay += w * bf2f((unsigned short)(v >> 16));
        }
    }
    axo = ax; ayo = ay;
}

// ---------------- mega kernel: GEMM1 (x@W1) blocks + deg blocks + bounds blocks ----------------
__global__ __launch_bounds__(256) void mega1_k(const int* flags, const void* x,
                                               const unsigned short* wtp, unsigned short* outp,
                                               const unsigned int* eu, int* deg,
                                               const unsigned int* bu, int* starts) {
    int b = blockIdx.x;
    int tid = threadIdx.x;
    if (b < GBK) {
        // ---- GEMM1: out[64x128] = x[64x128] @ W1; W frags read direct (L1-resident 32KB) ----
        __shared__ unsigned short As[64][136];
        int row0 = b * 64;
        int isbf = flags[0];
        if (isbf) {
            const unsigned short* inb = (const unsigned short*)x;
            for (int it = tid; it < 1024; it += 256) {
                int r = it >> 4, seg = it & 15;
                int gr = row0 + r;
                uint4 v = make_uint4(0u, 0u, 0u, 0u);
                if (gr < NN) v = ((const uint4*)inb)[(size_t)gr * 16 + seg];
                *(uint4*)&As[r][seg * 8] = v;
            }
        } else {
            const float* inf = (const float*)x;
            for (int it = tid; it < 1024; it += 256) {
                int r = it >> 4, seg = it & 15;
                int gr = row0 + r;
                unsigned short tmp[8];
                if (gr < NN) {
#pragma unroll
                    for (int q = 0; q < 8; q++) tmp[q] = f2bf(inf[(size_t)gr * 128 + seg * 8 + q]);
                } else {
#pragma unroll
                    for (int q = 0; q < 8; q++) tmp[q] = 0;
                }
#pragma unroll
                for (int q = 0; q < 8; q++) As[r][seg * 8 + q] = tmp[q];
            }
        }
        __syncthreads();
        int wv = tid >> 6, lane = tid & 63;
        int m = lane & 15, quad = lane >> 4;
        int arow = wv * 16 + m;
        bf16x8 af[4];
#pragma unroll
        for (int ks = 0; ks < 4; ks++)
            af[ks] = *(const bf16x8*)&As[arow][ks * 32 + quad * 8];
        int grbase = row0 + wv * 16;
#pragma unroll
        for (int tile = 0; tile < 8; tile++) {
            f32x4 acc = {0.f, 0.f, 0.f, 0.f};
            int n = tile * 16 + m;
#pragma unroll
            for (int ks = 0; ks < 4; ks++) {
                bf16x8 bfr = *(const bf16x8*)&wtp[(size_t)n * 128 + ks * 32 + quad * 8];
                acc = __builtin_amdgcn_mfma_f32_16x16x32_bf16(af[ks], bfr, acc, 0, 0, 0);
            }
#pragma unroll
            for (int r = 0; r < 4; r++) {
                int orow = grbase + quad * 4 + r;
                if (orow < NN) outp[(size_t)orow * 128 + n] = f2bf(acc[r]);
            }
        }
    } else if (b < GBK + EBK) {
        // ---- degree count ----
        int i = (b - GBK) * 256 + tid;
        if (i < EE) {
            int d;
            if (flags[1]) d = (int)((const uint2*)eu)[(long)EE + i].x;
            else          d = (int)eu[EE + i];
            d = ((unsigned)d < NN) ? d : 0;
            atomicAdd(&deg[d], 1);
        }
    } else {
        // ---- graph run boundaries ----
        int n = (b - GBK - EBK) * 256 + tid;
        if (n < NN) {
            int i64 = flags[1];
            int g = (int)(i64 ? bu[2 * (long)n] : bu[n]);
            g = ((unsigned)g < NG) ? g : 0;
            int gp = -1;
            if (n > 0) {
                gp = (int)(i64 ? bu[2 * (long)(n - 1)] : bu[n - 1]);
                gp = ((unsigned)gp < NG) ? gp : 0;
            }
            for (int gg = gp + 1; gg <= g; gg++) starts[gg] = n;
            if (n == NN - 1) {
                for (int gg = g + 1; gg <= NG; gg++) starts[gg] = NN;
            }
        }
    }
}

// ---------------- fused: 64 rows of agg(tin)+bias(+relu) -> MFMA with W -> tout ----------------
__global__ __launch_bounds__(256) void fuse_k(const unsigned short* tin, const unsigned short* wtp,
                                              const float* bias, const int* rowptr,
                                              const unsigned short* colsrc, const float* dinv,
                                              int relu, unsigned short* tout) {
    __shared__ unsigned short As[64][136];
    int tid = threadIdx.x;
    int row0 = blockIdx.x * 64;
    int wv = tid >> 6, lane = tid & 63;

    // each wave aggregates 16 consecutive rows into LDS (packed 2xbf16 per lane)
    for (int i = 0; i < 16; i++) {
        int n = row0 + wv * 16 + i;
        unsigned int o = 0u;
        if (n < NN) {
            float ax, ay;
            agg_node(tin, n, lane, bias, rowptr, colsrc, dinv, ax, ay);
            if (relu) { ax = fmaxf(ax, 0.f); ay = fmaxf(ay, 0.f); }
            o = (unsigned int)f2bf(ax) | ((unsigned int)f2bf(ay) << 16);
        }
        ((unsigned int*)&As[wv * 16 + i][0])[lane] = o;
    }
    __syncthreads();

    int m = lane & 15, quad = lane >> 4;
    int arow = wv * 16 + m;
    bf16x8 af[4];
#pragma unroll
    for (int ks = 0; ks < 4; ks++)
        af[ks] = *(const bf16x8*)&As[arow][ks * 32 + quad * 8];
    int grbase = row0 + wv * 16;
#pragma unroll
    for (int tile = 0; tile < 8; tile++) {
        f32x4 acc = {0.f, 0.f, 0.f, 0.f};
        int n = tile * 16 + m;
#pragma unroll
        for (int ks = 0; ks < 4; ks++) {
            bf16x8 bfr = *(const bf16x8*)&wtp[(size_t)n * 128 + ks * 32 + quad * 8];
            acc = __builtin_amdgcn_mfma_f32_16x16x32_bf16(af[ks], bfr, acc, 0, 0, 0);
        }
#pragma unroll
        for (int r = 0; r < 4; r++) {
            int orow = grbase + quad * 4 + r;
            if (orow < NN) tout[(size_t)orow * 128 + n] = f2bf(acc[r]);
        }
    }
}

// ---------------- fused: final agg (no relu) -> per-graph f32 atomic pool ----------------
__global__ __launch_bounds__(256) void aggpool_k(const unsigned short* tin, const float* bias,
                                                 const int* rowptr, const unsigned short* colsrc,
                                                 const float* dinv, const unsigned int* bu,
                                                 const int* flags, float* pooled) {
    int tid = threadIdx.x;
    int wv = tid >> 6, lane = tid & 63;
    int base = blockIdx.x * 64 + wv * 16;
    int i64 = flags[1];
    float gax = 0.f, gay = 0.f;
    int gcur = -1;
    for (int i = 0; i < 16; i++) {
        int n = base + i;
        if (n >= NN) break;
        int g = (int)(i64 ? bu[2 * (long)n] : bu[n]);
        g = ((unsigned)g < NG) ? g : 0;
        if (g != gcur) {
            if (gcur >= 0) {
                atomicAdd(&pooled[gcur * 128 + 2 * lane], gax);
                atomicAdd(&pooled[gcur * 128 + 2 * lane + 1], gay);
            }
            gax = 0.f; gay = 0.f; gcur = g;
        }
        float ax, ay;
        agg_node(tin, n, lane, bias, rowptr, colsrc, dinv, ax, ay);
        gax += ax; gay += ay;
    }
    if (gcur >= 0) {
        atomicAdd(&pooled[gcur * 128 + 2 * lane], gax);
        atomicAdd(&pooled[gcur * 128 + 2 * lane + 1], gay);
    }
}

// ---------------- head: pooled/cnt @ lin_w + lin_b ----------------
__global__ __launch_bounds__(128) void head_k(const float* pooled, const int* starts,
                                              const float* lwf, const float* lbf,
                                              void* outp, const int* flags) {
    __shared__ float p[128];
    int g = blockIdx.x, t = threadIdx.x;
    int c = starts[g + 1] - starts[g]; if (c < 1) c = 1;
    p[t] = pooled[g * 128 + t] / (float)c;
    __syncthreads();
    if (t < NC) {
        float o = lbf[t];
#pragma unroll 16
        for (int f = 0; f < 128; f++) o += p[f] * lwf[f * NC + t];
        if (flags[0]) ((unsigned short*)outp)[g * NC + t] = f2bf(o);
        else          ((float*)outp)[g * NC + t] = o;
    }
}

extern "C" void kernel_launch(void* const* d_in, const int* in_sizes, int n_in,
                              void* d_out, int out_size, void* d_ws, size_t ws_size,
                              hipStream_t stream) {
    char* ws = (char*)d_ws;
    size_t off = 0;
    auto alloc = [&](size_t bytes) { size_t o = off; off = (off + bytes + 255) & ~(size_t)255; return o; };

    int*   flags  = (int*)(ws + alloc(32 * 4));
    int*   deg    = (int*)(ws + alloc((size_t)NN * 4));
    int*   rowptr = (int*)(ws + alloc((size_t)(NN + 1) * 4));
    int*   pos    = (int*)(ws + alloc((size_t)NN * 4));
    int*   bsum   = (int*)(ws + alloc((size_t)256 * 4));
    int*   bofs   = (int*)(ws + alloc((size_t)256 * 4));
    int*   starts = (int*)(ws + alloc((size_t)(NG + 1) * 4));
    unsigned short* colsrc = (unsigned short*)(ws + alloc((size_t)EE * 2));
    float* dinv   = (float*)(ws + alloc((size_t)NN * 4));
    unsigned short* wt  = (unsigned short*)(ws + alloc((size_t)3 * 16384 * 2));
    float* bfv    = (float*)(ws + alloc((size_t)3 * 128 * 4));
    float* lwf    = (float*)(ws + alloc((size_t)1280 * 4));
    float* lbf    = (float*)(ws + alloc((size_t)16 * 4));
    float* pooled = (float*)(ws + alloc((size_t)NG * 128 * 4));
    unsigned short* tbuf = (unsigned short*)(ws + alloc((size_t)NN * 128 * 2));
    unsigned short* hbuf = (unsigned short*)(ws + alloc((size_t)NN * 128 * 2));

    const void* x = d_in[0];
    const unsigned int* eu = (const unsigned int*)d_in[1];
    const unsigned int* bu = (const unsigned int*)d_in[2];

    hipMemsetAsync(deg, 0, (size_t)NN * 4, stream);

    detect_k<<<1, 256, 0, stream>>>((const unsigned short*)x, eu, flags);
    cvt_params_k<<<199, 256, 0, stream>>>(flags, d_in[3], d_in[4], d_in[5], d_in[6],
                                          d_in[7], d_in[8], d_in[9], d_in[10],
                                          wt, bfv, lwf, lbf, pooled);

    // GEMM1 + degree count + graph bounds, overlapped in one launch
    mega1_k<<<GBK + EBK + NBK, 256, 0, stream>>>(flags, x, wt, tbuf, eu, deg, bu, starts);

    int nblk = NBK;
    bsum_k<<<nblk, 256, 0, stream>>>(deg, bsum);
    bscan_k<<<1, 256, 0, stream>>>(bsum, bofs, nblk, rowptr);
    scan3_k<<<nblk, 256, 0, stream>>>(deg, bofs, rowptr, pos, dinv);
    fill_k<<<(EE + 255) / 256, 256, 0, stream>>>(flags, eu, pos, colsrc);

    // layer1 agg (+relu,b1) fused with GEMM2
    fuse_k<<<GBK, 256, 0, stream>>>(tbuf, wt + 16384, bfv, rowptr, colsrc, dinv, 1, hbuf);
    // layer2 agg (+relu,b2) fused with GEMM3
    fuse_k<<<GBK, 256, 0, stream>>>(hbuf, wt + 32768, bfv + 128, rowptr, colsrc, dinv, 1, tbuf);
    // layer3 agg (b3, no relu) fused with per-graph f32 pooling
    aggpool_k<<<GBK, 256, 0, stream>>>(tbuf, bfv + 256, rowptr, colsrc, dinv, bu, flags, pooled);

    head_k<<<NG, 128, 0, stream>>>(pooled, starts, lwf, lbf, d_out, flags);
}

// Round 2
// 355.801 us; speedup vs baseline: 1.0095x; 1.0095x over previous
//
#include <hip/hip_runtime.h>
#include <hip/hip_bf16.h>

#define NN 50000
#define EE 800000
#define FD 128
#define NG 128
#define NC 10
#define GBK 782   // (NN+63)/64
#define EBK 3125  // (EE+255)/256
#define NBK 196   // (NN+255)/256

typedef __attribute__((ext_vector_type(8))) short bf16x8;
typedef __attribute__((ext_vector_type(4))) float f32x4;

__device__ __forceinline__ float bf2f(unsigned short u) {
    return __uint_as_float(((unsigned int)u) << 16);
}
__device__ __forceinline__ unsigned short f2bf(float f) {
    unsigned int u = __float_as_uint(f);
    unsigned int r = (u >> 16) & 1u;
    u += 0x7fffu + r;
    return (unsigned short)(u >> 16);
}
__device__ __forceinline__ float ldf(const void* p, long i, int bf) {
    return bf ? bf2f(((const unsigned short*)p)[i]) : ((const float*)p)[i];
}

// ---------------- dtype detection ----------------
__global__ void detect_k(const unsigned short* xu, const unsigned int* eu, int* flags) {
    __shared__ int sbig, snz;
    if (threadIdx.x == 0) { sbig = 0; snz = 0; }
    __syncthreads();
    int t = threadIdx.x;
    float f = bf2f(xu[t * 2]);
    if (!(fabsf(f) < 1.0e6f)) atomicOr(&sbig, 1);
    if (eu[t * 2 + 1] != 0u) atomicOr(&snz, 1);
    __syncthreads();
    if (t == 0) {
        flags[0] = sbig ? 0 : 1;
        flags[1] = snz ? 0 : 1;
    }
}

// ---------------- params conversion + pooled zeroing ----------------
__global__ void cvt_params_k(const int* flags,
                             const void* w1, const void* b1, const void* w2, const void* b2,
                             const void* w3, const void* b3, const void* lw, const void* lb,
                             unsigned short* wt, float* bfv, float* lwf, float* lbf,
                             float* pooled) {
    int i = blockIdx.x * 256 + threadIdx.x;
    int bf = flags[0];
    if (i < 16384) pooled[i] = 0.f;
    if (i < 16384) {
        int k = i >> 7, n = i & 127;
        wt[n * 128 + k] = f2bf(ldf(w1, i, bf));
    } else if (i < 32768) {
        int j = i - 16384; int k = j >> 7, n = j & 127;
        wt[16384 + n * 128 + k] = f2bf(ldf(w2, j, bf));
    } else if (i < 49152) {
        int j = i - 32768; int k = j >> 7, n = j & 127;
        wt[32768 + n * 128 + k] = f2bf(ldf(w3, j, bf));
    }
    else if (i < 49280)  bfv[i - 49152] = ldf(b1, i - 49152, bf);
    else if (i < 49408)  bfv[i - 49152] = ldf(b2, i - 49280, bf);
    else if (i < 49536)  bfv[i - 49152] = ldf(b3, i - 49408, bf);
    else if (i < 50816)  lwf[i - 49536] = ldf(lw, i - 49536, bf);
    else if (i < 50826)  lbf[i - 50816] = ldf(lb, i - 50816, bf);
}

// ---------------- scan K1: per-block sums ----------------
__global__ __launch_bounds__(256) void bsum_k(const int* deg, int* bsum) {
    __shared__ int sd[256];
    int i = blockIdx.x * 256 + threadIdx.x;
    sd[threadIdx.x] = (i < NN) ? deg[i] : 0;
    __syncthreads();
    for (int s = 128; s > 0; s >>= 1) {
        if (threadIdx.x < s) sd[threadIdx.x] += sd[threadIdx.x + s];
        __syncthreads();
    }
    if (threadIdx.x == 0) bsum[blockIdx.x] = sd[0];
}

// ---------------- scan K2: single-block exclusive scan ----------------
__global__ __launch_bounds__(256) void bscan_k(const int* bsum, int* bofs, int nblk, int* rowptr) {
    __shared__ int sb[256];
    int t = threadIdx.x;
    sb[t] = (t < nblk) ? bsum[t] : 0;
    __syncthreads();
    if (t == 0) {
        int a = 0;
        for (int b = 0; b < nblk; b++) { int v = sb[b]; sb[b] = a; a += v; }
        rowptr[NN] = a;
    }
    __syncthreads();
    if (t < nblk) bofs[t] = sb[t];
}

// ---------------- scan K3: per-block Hillis-Steele, fused dinv ----------------
__global__ __launch_bounds__(256) void scan3_k(const int* deg, const int* bofs,
                                               int* rowptr, int* pos, float* dinv) {
    __shared__ int sd[256];
    int b = blockIdx.x, t = threadIdx.x;
    int i = b * 256 + t;
    int v = (i < NN) ? deg[i] : 0;
    sd[t] = v;
    __syncthreads();
    for (int off = 1; off < 256; off <<= 1) {
        int add = (t >= off) ? sd[t - off] : 0;
        __syncthreads();
        sd[t] += add;
        __syncthreads();
    }
    int excl = bofs[b] + sd[t] - v;
    if (i < NN) {
        rowptr[i] = excl; pos[i] = excl;
        dinv[i] = rsqrtf((float)(v + 1));
    }
}

// ---------------- CSR fill: colsrc + precomputed edge weight wnorm = dinv[src] ----------------
__global__ void fill_k(const int* flags, const unsigned int* eu, int* pos,
                       unsigned short* colsrc, float* wnorm, const float* dinv) {
    int e = blockIdx.x * 256 + threadIdx.x;
    if (e >= EE) return;
    int s, d;
    if (flags[1]) {
        s = (int)((const uint2*)eu)[e].x;
        d = (int)((const uint2*)eu)[(long)EE + e].x;
    } else {
        s = (int)eu[e];
        d = (int)eu[EE + e];
    }
    s = ((unsigned)s < NN) ? s : 0;
    d = ((unsigned)d < NN) ? d : 0;
    float ws = dinv[s];                 // independent of the atomic, issues in parallel
    int idx = atomicAdd(&pos[d], 1);
    if ((unsigned)idx < EE) { colsrc[idx] = (unsigned short)s; wnorm[idx] = ws; }
}

// ---------------- per-node aggregation: 2-deep chain, 16 gathers in flight ----------------
__device__ __forceinline__ void agg_node2(const unsigned short* t, int n, int lane,
                                          const float* bias, const int* rowptr,
                                          const unsigned short* colsrc, const float* wnorm,
                                          const float* dinv, float& axo, float& ayo) {
    float dn = dinv[n];
    unsigned int sf = ((const unsigned int*)(t + (size_t)n * 128))[lane];
    // self-loop: dn^2 * v  ==  dn * (dn * v); dn is factored out of the edge sum below
    float sx0 = dn * bf2f((unsigned short)(sf & 0xffffu));
    float sy0 = dn * bf2f((unsigned short)(sf >> 16));
    float sx1 = 0.f, sy1 = 0.f;
    int j0 = rowptr[n];
    int cnt = rowptr[n + 1] - j0;
    for (int e0 = 0; e0 < cnt; e0 += 64) {
        int m = cnt - e0; if (m > 64) m = 64;
        int idx = 0; float w = 0.f;
        if (lane < m) {
            idx = (int)colsrc[j0 + e0 + lane];
            idx = ((unsigned)idx < NN) ? idx : 0;
            w = wnorm[j0 + e0 + lane];
        }
        int e = 0;
        for (; e + 15 < m; e += 16) {
            int s[16]; float wr[16]; unsigned int v[16];
#pragma unroll
            for (int i = 0; i < 16; i++) { s[i] = __shfl(idx, e + i); wr[i] = __shfl(w, e + i); }
#pragma unroll
            for (int i = 0; i < 16; i++)
                v[i] = ((const unsigned int*)(t + (size_t)s[i] * 128))[lane];
#pragma unroll
            for (int i = 0; i < 16; i++) {
                float lo = bf2f((unsigned short)(v[i] & 0xffffu));
                float hi = bf2f((unsigned short)(v[i] >> 16));
                if (i & 1) { sx1 += wr[i] * lo; sy1 += wr[i] * hi; }
                else       { sx0 += wr[i] * lo; sy0 += wr[i] * hi; }
            }
        }
        for (; e + 3 < m; e += 4) {
            int s0 = __shfl(idx, e),     s1 = __shfl(idx, e + 1);
            int s2 = __shfl(idx, e + 2), s3 = __shfl(idx, e + 3);
            float w0 = __shfl(w, e),     w1 = __shfl(w, e + 1);
            float w2 = __shfl(w, e + 2), w3 = __shfl(w, e + 3);
            unsigned int v0 = ((const unsigned int*)(t + (size_t)s0 * 128))[lane];
            unsigned int v1 = ((const unsigned int*)(t + (size_t)s1 * 128))[lane];
            unsigned int v2 = ((const unsigned int*)(t + (size_t)s2 * 128))[lane];
            unsigned int v3 = ((const unsigned int*)(t + (size_t)s3 * 128))[lane];
            sx0 += w0 * bf2f((unsigned short)(v0 & 0xffffu));
            sy0 += w0 * bf2f((unsigned short)(v0 >> 16));
            sx1 += w1 * bf2f((unsigned short)(v1 & 0xffffu));
            sy1 += w1 * bf2f((unsigned short)(v1 >> 16));
            sx0 += w2 * bf2f((unsigned short)(v2 & 0xffffu));
            sy0 += w2 * bf2f((unsigned short)(v2 >> 16));
            sx1 += w3 * bf2f((unsigned short)(v3 & 0xffffu));
            sy1 += w3 * bf2f((unsigned short)(v3 >> 16));
        }
        for (; e < m; e++) {
            int s = __shfl(idx, e);
            float we = __shfl(w, e);
            unsigned int v = ((const unsigned int*)(t + (size_t)s * 128))[lane];
            sx0 += we * bf2f((unsigned short)(v & 0xffffu));
            sy0 += we * bf2f((unsigned short)(v >> 16));
        }
    }
    axo = bias[2 * lane]     + dn * (sx0 + sx1);
    ayo = bias[2 * lane + 1] + dn * (sy0 + sy1);
}

// ---------------- aggregation kernel: one wave per node ----------------
__global__ __launch_bounds__(256) void agg_k(const unsigned short* t, unsigned short* outp,
                                             const float* bias, const int* rowptr,
                                             const unsigned short* colsrc, const float* wnorm,
                                             const float* dinv, int relu) {
    int gtid = blockIdx.x * 256 + threadIdx.x;
    int n = gtid >> 6;
    int lane = threadIdx.x & 63;
    if (n >= NN) return;
    float ax, ay;
    agg_node2(t, n, lane, bias, rowptr, colsrc, wnorm, dinv, ax, ay);
    if (relu) { ax = fmaxf(ax, 0.f); ay = fmaxf(ay, 0.f); }
    unsigned int o = (unsigned int)f2bf(ax) | ((unsigned int)f2bf(ay) << 16);
    ((unsigned int*)(outp + (size_t)n * 128))[lane] = o;
}

// ---------------- final agg + per-graph f32 pool (block-merged atomics) ----------------
__global__ __launch_bounds__(256) void aggpool_k(const unsigned short* t, const float* bias,
                                                 const int* rowptr, const unsigned short* colsrc,
                                                 const float* wnorm, const float* dinv,
                                                 const unsigned int* bu, const int* flags,
                                                 float* pooled) {
    __shared__ float sacc[4][128];
    __shared__ int sg[4];
    int tid = threadIdx.x, wv = tid >> 6, lane = tid & 63;
    int n = blockIdx.x * 4 + wv;
    int i64 = flags[1];
    float ax = 0.f, ay = 0.f;
    int g = -1;
    if (n < NN) {
        g = (int)(i64 ? bu[2 * (long)n] : bu[n]);
        g = ((unsigned)g < NG) ? g : 0;
        agg_node2(t, n, lane, bias, rowptr, colsrc, wnorm, dinv, ax, ay);
    }
    sacc[wv][2 * lane] = ax;
    sacc[wv][2 * lane + 1] = ay;
    if (lane == 0) sg[wv] = g;
    __syncthreads();
    if (tid < 128) {
        float acc = 0.f; int curg = -1;
        for (int w2 = 0; w2 < 4; w2++) {
            int gg = sg[w2];
            if (gg < 0) continue;
            if (gg == curg) acc += sacc[w2][tid];
            else {
                if (curg >= 0) atomicAdd(&pooled[curg * 128 + tid], acc);
                curg = gg; acc = sacc[w2][tid];
            }
        }
        if (curg >= 0) atomicAdd(&pooled[curg * 128 + tid], acc);
    }
}

// ---------------- mega kernel: GEMM1 (x@W1) + deg + bounds ----------------
__global__ __launch_bounds__(256) void mega1_k(const int* flags, const void* x,
                                               const unsigned short* wtp, unsigned short* outp,
                                               const unsigned int* eu, int* deg,
                                               const unsigned int* bu, int* starts) {
    int b = blockIdx.x;
    int tid = threadIdx.x;
    if (b < GBK) {
        __shared__ unsigned short As[64][136];
        int row0 = b * 64;
        int isbf = flags[0];
        if (isbf) {
            const unsigned short* inb = (const unsigned short*)x;
            for (int it = tid; it < 1024; it += 256) {
                int r = it >> 4, seg = it & 15;
                int gr = row0 + r;
                uint4 v = make_uint4(0u, 0u, 0u, 0u);
                if (gr < NN) v = ((const uint4*)inb)[(size_t)gr * 16 + seg];
                *(uint4*)&As[r][seg * 8] = v;
            }
        } else {
            const float* inf = (const float*)x;
            for (int it = tid; it < 1024; it += 256) {
                int r = it >> 4, seg = it & 15;
                int gr = row0 + r;
                unsigned short tmp[8];
                if (gr < NN) {
#pragma unroll
                    for (int q = 0; q < 8; q++) tmp[q] = f2bf(inf[(size_t)gr * 128 + seg * 8 + q]);
                } else {
#pragma unroll
                    for (int q = 0; q < 8; q++) tmp[q] = 0;
                }
#pragma unroll
                for (int q = 0; q < 8; q++) As[r][seg * 8 + q] = tmp[q];
            }
        }
        __syncthreads();
        int wv = tid >> 6, lane = tid & 63;
        int m = lane & 15, quad = lane >> 4;
        int arow = wv * 16 + m;
        bf16x8 af[4];
#pragma unroll
        for (int ks = 0; ks < 4; ks++)
            af[ks] = *(const bf16x8*)&As[arow][ks * 32 + quad * 8];
        int grbase = row0 + wv * 16;
#pragma unroll
        for (int tile = 0; tile < 8; tile++) {
            f32x4 acc = {0.f, 0.f, 0.f, 0.f};
            int n = tile * 16 + m;
#pragma unroll
            for (int ks = 0; ks < 4; ks++) {
                bf16x8 bfr = *(const bf16x8*)&wtp[(size_t)n * 128 + ks * 32 + quad * 8];
                acc = __builtin_amdgcn_mfma_f32_16x16x32_bf16(af[ks], bfr, acc, 0, 0, 0);
            }
#pragma unroll
            for (int r = 0; r < 4; r++) {
                int orow = grbase + quad * 4 + r;
                if (orow < NN) outp[(size_t)orow * 128 + n] = f2bf(acc[r]);
            }
        }
    } else if (b < GBK + EBK) {
        int i = (b - GBK) * 256 + tid;
        if (i < EE) {
            int d;
            if (flags[1]) d = (int)((const uint2*)eu)[(long)EE + i].x;
            else          d = (int)eu[EE + i];
            d = ((unsigned)d < NN) ? d : 0;
            atomicAdd(&deg[d], 1);
        }
    } else {
        int n = (b - GBK - EBK) * 256 + tid;
        if (n < NN) {
            int i64 = flags[1];
            int g = (int)(i64 ? bu[2 * (long)n] : bu[n]);
            g = ((unsigned)g < NG) ? g : 0;
            int gp = -1;
            if (n > 0) {
                gp = (int)(i64 ? bu[2 * (long)(n - 1)] : bu[n - 1]);
                gp = ((unsigned)gp < NG) ? gp : 0;
            }
            for (int gg = gp + 1; gg <= g; gg++) starts[gg] = n;
            if (n == NN - 1) {
                for (int gg = g + 1; gg <= NG; gg++) starts[gg] = NN;
            }
        }
    }
}

// ---------------- LDS-free bf16 GEMM: 64 rows/block, A and W straight from global ----------------
__global__ __launch_bounds__(256) void gemm_direct_k(const unsigned short* in,
                                                     const unsigned short* wtp,
                                                     unsigned short* outp, int nrows) {
    int tid = threadIdx.x;
    int wv = tid >> 6, lane = tid & 63;
    int m = lane & 15, quad = lane >> 4;
    int row0 = blockIdx.x * 64;
    int arow = row0 + wv * 16 + m;
    int srow = (arow < nrows) ? arow : 0;   // clamp; stores are guarded
    const unsigned short* rp = in + (size_t)srow * 128;
    bf16x8 af[4];
#pragma unroll
    for (int ks = 0; ks < 4; ks++)
        af[ks] = *(const bf16x8*)&rp[ks * 32 + quad * 8];
    int grbase = row0 + wv * 16;
#pragma unroll
    for (int tile = 0; tile < 8; tile++) {
        f32x4 acc = {0.f, 0.f, 0.f, 0.f};
        int n = tile * 16 + m;
#pragma unroll
        for (int ks = 0; ks < 4; ks++) {
            bf16x8 bfr = *(const bf16x8*)&wtp[(size_t)n * 128 + ks * 32 + quad * 8];
            acc = __builtin_amdgcn_mfma_f32_16x16x32_bf16(af[ks], bfr, acc, 0, 0, 0);
        }
#pragma unroll
        for (int r = 0; r < 4; r++) {
            int orow = grbase + quad * 4 + r;
            if (orow < nrows) outp[(size_t)orow * 128 + n] = f2bf(acc[r]);
        }
    }
}

// ---------------- head: pooled/cnt @ lin_w + lin_b ----------------
__global__ __launch_bounds__(128) void head_k(const float* pooled, const int* starts,
                                              const float* lwf, const float* lbf,
                                              void* outp, const int* flags) {
    __shared__ float p[128];
    int g = blockIdx.x, t = threadIdx.x;
    int c = starts[g + 1] - starts[g]; if (c < 1) c = 1;
    p[t] = pooled[g * 128 + t] / (float)c;
    __syncthreads();
    if (t < NC) {
        float o = lbf[t];
#pragma unroll 16
        for (int f = 0; f < 128; f++) o += p[f] * lwf[f * NC + t];
        if (flags[0]) ((unsigned short*)outp)[g * NC + t] = f2bf(o);
        else          ((float*)outp)[g * NC + t] = o;
    }
}

extern "C" void kernel_launch(void* const* d_in, const int* in_sizes, int n_in,
                              void* d_out, int out_size, void* d_ws, size_t ws_size,
                              hipStream_t stream) {
    char* ws = (char*)d_ws;
    size_t off = 0;
    auto alloc = [&](size_t bytes) { size_t o = off; off = (off + bytes + 255) & ~(size_t)255; return o; };

    int*   flags  = (int*)(ws + alloc(32 * 4));
    int*   deg    = (int*)(ws + alloc((size_t)NN * 4));
    int*   rowptr = (int*)(ws + alloc((size_t)(NN + 1) * 4));
    int*   pos    = (int*)(ws + alloc((size_t)NN * 4));
    int*   bsum   = (int*)(ws + alloc((size_t)256 * 4));
    int*   bofs   = (int*)(ws + alloc((size_t)256 * 4));
    int*   starts = (int*)(ws + alloc((size_t)(NG + 1) * 4));
    unsigned short* colsrc = (unsigned short*)(ws + alloc((size_t)EE * 2));
    float* wnorm  = (float*)(ws + alloc((size_t)EE * 4));
    float* dinv   = (float*)(ws + alloc((size_t)NN * 4));
    unsigned short* wt  = (unsigned short*)(ws + alloc((size_t)3 * 16384 * 2));
    float* bfv    = (float*)(ws + alloc((size_t)3 * 128 * 4));
    float* lwf    = (float*)(ws + alloc((size_t)1280 * 4));
    float* lbf    = (float*)(ws + alloc((size_t)16 * 4));
    float* pooled = (float*)(ws + alloc((size_t)NG * 128 * 4));
    unsigned short* tbuf = (unsigned short*)(ws + alloc((size_t)NN * 128 * 2));
    unsigned short* hbuf = (unsigned short*)(ws + alloc((size_t)NN * 128 * 2));

    const void* x = d_in[0];
    const unsigned int* eu = (const unsigned int*)d_in[1];
    const unsigned int* bu = (const unsigned int*)d_in[2];

    hipMemsetAsync(deg, 0, (size_t)NN * 4, stream);

    detect_k<<<1, 256, 0, stream>>>((const unsigned short*)x, eu, flags);
    cvt_params_k<<<199, 256, 0, stream>>>(flags, d_in[3], d_in[4], d_in[5], d_in[6],
                                          d_in[7], d_in[8], d_in[9], d_in[10],
                                          wt, bfv, lwf, lbf, pooled);

    // GEMM1 + degree count + graph bounds, overlapped in one launch
    mega1_k<<<GBK + EBK + NBK, 256, 0, stream>>>(flags, x, wt, tbuf, eu, deg, bu, starts);

    bsum_k<<<NBK, 256, 0, stream>>>(deg, bsum);
    bscan_k<<<1, 256, 0, stream>>>(bsum, bofs, NBK, rowptr);
    scan3_k<<<NBK, 256, 0, stream>>>(deg, bofs, rowptr, pos, dinv);
    fill_k<<<(EE + 255) / 256, 256, 0, stream>>>(flags, eu, pos, colsrc, wnorm, dinv);

    int agg_blocks = (NN * 64 + 255) / 256;   // one wave per node
    agg_k<<<agg_blocks, 256, 0, stream>>>(tbuf, hbuf, bfv, rowptr, colsrc, wnorm, dinv, 1);
    gemm_direct_k<<<GBK, 256, 0, stream>>>(hbuf, wt + 16384, tbuf, NN);
    agg_k<<<agg_blocks, 256, 0, stream>>>(tbuf, hbuf, bfv + 128, rowptr, colsrc, wnorm, dinv, 1);
    gemm_direct_k<<<GBK, 256, 0, stream>>>(hbuf, wt + 32768, tbuf, NN);
    aggpool_k<<<(NN + 3) / 4, 256, 0, stream>>>(tbuf, bfv + 256, rowptr, colsrc, wnorm, dinv,
                                                bu, flags, pooled);

    head_k<<<NG, 128, 0, stream>>>(pooled, starts, lwf, lbf, d_out, flags);
}